// Round 12
// baseline (6239.405 us; speedup 1.0000x reference)
//
#include <hip/hip_runtime.h>
#include <math.h>

#define Bn 128
#define Tn 256
#define Fn 36
#define Hn 128
#define G4 512
#define BTFn (Bn*Tn*Fn)
#define TF 9216

// ws float offsets
#define INVD_OFF 0
#define LOSS_OFF 102656
#define IMP_OFF  103040

// ---- LDS word offsets (r11 map; GFB retained but unused) ----
#define OFF_WHH    0       // [kk4<32][e<2][r<512] f16-pairs : 32768
#define OFF_WHIST  32768   // [q<64][f<36]                   : 2304
#define OFF_WF     35072   // [q<18][g<36] diag-zeroed       : 648
#define OFF_WWC    35720   // [q<36][g<36]                   : 1296
#define OFF_IN     37016   // f32 [c<2][w<5][f<36]           : 360
#define OFF_DP     37376   // [c<2][20]                      : 40
#define OFF_MP     37416   // [par<2][c<2][20]               : 80
#define OFF_GXP    37496   // [c<2][20]                      : 40
#define OFF_XCP    37536   // [c<2][20]                      : 40
#define OFF_CCP    37576   // [c<2][20]                      : 40
#define OFF_ALPHA  37616   // f32 [c<2][36]                  : 72
#define OFF_HP     37688   // [c<2][64] f16-pairs            : 128
#define OFF_GFA    37816   // f32 [c<2][512] final gates     : 1024
#define OFF_GFB    38840   // (unused)                       : 1024
#define OFF_INVD   39864   // f32 [256]
#define OFF_BH     40120   // 36
#define OFF_BF     40156   // 36
#define OFF_BWC    40192   // 36
#define SMEM_WORDS 40228   // 160912 B

typedef _Float16 h2_t __attribute__((ext_vector_type(2)));

__device__ __forceinline__ unsigned int bcu(float x) { return __builtin_bit_cast(unsigned int, x); }
__device__ __forceinline__ unsigned int pkh(float a, float b) {
    return __builtin_bit_cast(unsigned int, __builtin_amdgcn_cvt_pkrtz(a, b));
}
__device__ __forceinline__ float dot2(unsigned int a, unsigned int b, float c) {
    return __builtin_amdgcn_fdot2(__builtin_bit_cast(h2_t, a), __builtin_bit_cast(h2_t, b), c, false);
}
__device__ __forceinline__ float sigmoid_f(float x) {
    return __builtin_amdgcn_rcpf(1.f + __expf(-x));
}
__device__ __forceinline__ float tanh_f(float x) {
    return fmaf(2.f, __builtin_amdgcn_rcpf(1.f + __expf(-2.f * x)), -1.f);
}

// ---------------- prep: inv-denom per t ----------------
__global__ void prep_kernel(const float* __restrict__ data,
                            float* __restrict__ ws) {
    int t = blockIdx.x;
    int tid = threadIdx.x;
    __shared__ float red[256];
    float s = 0.f;
    for (int idx = tid; idx < Bn * Fn; idx += 256) {
        int b = idx / Fn, f = idx - b * Fn;
        s += data[((size_t)(b * 24 + 1) * Tn + t) * Fn + f];
    }
    red[tid] = s;
    __syncthreads();
    for (int off = 128; off > 0; off >>= 1) {
        if (tid < off) red[tid] += red[tid + off];
        __syncthreads();
    }
    if (tid == 0) ws[INVD_OFF + t] = 1.f / (red[0] + 1e-5f);
}

// 18 packed dots from LDS base (%4==0) against wih[woff..+17]
#define DOT18M(acc, base, woff) do {                                   \
    const unsigned int* _p = &smem[(base)];                            \
    float _a = 0.f, _b = 0.f;                                          \
    float4 _v0 = *(const float4*)_p;                                   \
    _a = dot2(bcu(_v0.x), wih[(woff) + 0], _a);                        \
    _b = dot2(bcu(_v0.y), wih[(woff) + 1], _b);                        \
    _a = dot2(bcu(_v0.z), wih[(woff) + 2], _a);                        \
    _b = dot2(bcu(_v0.w), wih[(woff) + 3], _b);                        \
    float4 _v1 = *(const float4*)(_p + 4);                             \
    _a = dot2(bcu(_v1.x), wih[(woff) + 4], _a);                        \
    _b = dot2(bcu(_v1.y), wih[(woff) + 5], _b);                        \
    _a = dot2(bcu(_v1.z), wih[(woff) + 6], _a);                        \
    _b = dot2(bcu(_v1.w), wih[(woff) + 7], _b);                        \
    float4 _v2 = *(const float4*)(_p + 8);                             \
    _a = dot2(bcu(_v2.x), wih[(woff) + 8], _a);                        \
    _b = dot2(bcu(_v2.y), wih[(woff) + 9], _b);                        \
    _a = dot2(bcu(_v2.z), wih[(woff) + 10], _a);                       \
    _b = dot2(bcu(_v2.w), wih[(woff) + 11], _b);                       \
    float4 _v3 = *(const float4*)(_p + 12);                            \
    _a = dot2(bcu(_v3.x), wih[(woff) + 12], _a);                       \
    _b = dot2(bcu(_v3.y), wih[(woff) + 13], _b);                       \
    _a = dot2(bcu(_v3.z), wih[(woff) + 14], _a);                       \
    _b = dot2(bcu(_v3.w), wih[(woff) + 15], _b);                       \
    float2 _v4 = *(const float2*)(_p + 16);                            \
    _a = dot2(bcu(_v4.x), wih[(woff) + 16], _a);                       \
    _b = dot2(bcu(_v4.y), wih[(woff) + 17], _b);                       \
    acc += _a + _b;                                                    \
} while (0)

// loader staging of one float4 (4 features) into LDS; P = MP parity
#define STAGE(v, P) do {                                                          \
    if (lw == 0) {                                                                \
        *(float4*)&smf[OFF_IN + lc * 180 + 4 * lu] = (v);                         \
        smem[OFF_MP + (P) * 40 + lc * 20 + 2 * lu]     = pkh((v).x, (v).y);       \
        smem[OFF_MP + (P) * 40 + lc * 20 + 2 * lu + 1] = pkh((v).z, (v).w);       \
    } else if (lw == 1) {                                                         \
        smem[OFF_DP + lc * 20 + 2 * lu]     = pkh((v).x, (v).y);                  \
        smem[OFF_DP + lc * 20 + 2 * lu + 1] = pkh((v).z, (v).w);                  \
        float _g0 = __expf(-fmaxf(fmaf((v).x, wdxd.x, bdx4.x), 0.f));             \
        float _g1 = __expf(-fmaxf(fmaf((v).y, wdxd.y, bdx4.y), 0.f));             \
        float _g2 = __expf(-fmaxf(fmaf((v).z, wdxd.z, bdx4.z), 0.f));             \
        float _g3 = __expf(-fmaxf(fmaf((v).w, wdxd.w, bdx4.w), 0.f));             \
        smem[OFF_GXP + lc * 20 + 2 * lu]     = pkh(_g0, _g1);                     \
        smem[OFF_GXP + lc * 20 + 2 * lu + 1] = pkh(_g2, _g3);                     \
    } else {                                                                      \
        *(float4*)&smf[OFF_IN + lc * 180 + lw * 36 + 4 * lu] = (v);               \
    }                                                                             \
} while (0)

// ---------------- main: 1024 threads (16 waves), 2 chains, 3 barriers/step ----------------
__global__ __launch_bounds__(1024) void rits_main(
    const float* __restrict__ data,
    const float* __restrict__ W_dh, const float* __restrict__ b_dh,
    const float* __restrict__ W_dx, const float* __restrict__ b_dx,
    const float* __restrict__ W_hist, const float* __restrict__ b_hist,
    const float* __restrict__ W_feat, const float* __restrict__ b_feat,
    const float* __restrict__ W_wc, const float* __restrict__ b_wc,
    const float* __restrict__ W_ih, const float* __restrict__ W_hh,
    const float* __restrict__ b_ih, const float* __restrict__ b_hh,
    const float* __restrict__ W_comb,
    float* __restrict__ ws) {

    extern __shared__ unsigned int smem[];
    float* smf = (float*)smem;

    const int tid = threadIdx.x;
    const int chainA = blockIdx.x * 2, chainB = chainA + 1;
    const int bA = chainA / 3, kA = chainA - 3 * bA;
    const int bB = chainB / 3, kB = chainB - 3 * bB;

    // ---- one-time staging ----
    for (int i = tid; i < 32768; i += 1024) {
        int kk4 = i >> 10, e = (i >> 9) & 1, r = i & 511;
        float2 wv = *(const float2*)&W_hh[r * Hn + kk4 * 4 + 2 * e];
        smem[OFF_WHH + i] = pkh(wv.x, wv.y);
    }
    for (int i = tid; i < 64 * Fn; i += 1024) {
        int q = i / Fn, f = i - q * Fn;
        float2 wv = *(const float2*)&W_hist[f * Hn + 2 * q];
        smem[OFF_WHIST + i] = pkh(wv.x, wv.y);
    }
    for (int i = tid; i < 18 * Fn; i += 1024) {
        int q = i / Fn, g = i - q * Fn;
        float2 wv = *(const float2*)&W_feat[g * Fn + 2 * q];
        float w0 = (2 * q     == g) ? 0.f : wv.x;
        float w1 = (2 * q + 1 == g) ? 0.f : wv.y;
        smem[OFF_WF + i] = pkh(w0, w1);
    }
    for (int i = tid; i < 36 * Fn; i += 1024) {
        int q = i / Fn, g = i - q * Fn;
        int col = (q < 18) ? 2 * q : Fn + 2 * (q - 18);
        float2 wv = *(const float2*)&W_wc[g * 2 * Fn + col];
        smem[OFF_WWC + i] = pkh(wv.x, wv.y);
    }
    if (tid < Fn) {
        smf[OFF_BH + tid] = b_hist[tid];
        smf[OFF_BF + tid] = b_feat[tid];
        smf[OFF_BWC + tid] = b_wc[tid];
    }
    for (int i = tid; i < Tn; i += 1024) smf[OFF_INVD + i] = ws[INVD_OFF + i];
    if (tid < 128) smem[OFF_HP + tid] = 0;

    // ---- role-private registers ----
    // hh role (256<=tid<768): gate row j
    unsigned int wih[36];
    float bias_j = 0.f;
    if (tid >= 256 && tid < 768) {
        const int j = tid - 256;
        #pragma unroll
        for (int q = 0; q < 36; ++q) {
            float2 wv = *(const float2*)&W_ih[j * 2 * Fn + 2 * q];
            wih[q] = pkh(wv.x, wv.y);
        }
        bias_j = b_ih[j] + b_hh[j];
    }
    // LSTM role (tid>=768): unit (c,u)
    unsigned int wdh[18];
    float bdh_reg = 0.f;
    if (tid >= 768) {
        int u = (tid - 768) & 127;
        #pragma unroll
        for (int q = 0; q < 18; ++q) {
            float2 wv = *(const float2*)&W_dh[u * Fn + 2 * q];
            wdh[q] = pkh(wv.x, wv.y);
        }
        bdh_reg = b_dh[u];
    }
    // loader role (128<=tid<218)
    const float* ldsrc = nullptr; int lw = 0, lc = 0, lu = 0;
    float4 wdxd = {0,0,0,0}, bdx4 = {0,0,0,0};
    if (tid >= 128 && tid < 218) {
        int idx = tid - 128;
        lc = idx / 45; int r = idx - 45 * lc;
        lw = r / 9; lu = r - 9 * lw;
        int bb = lc ? bB : bA, kk = lc ? kB : kA;
        int row = (lw == 0) ? 1 : (lw == 1) ? 2 : (3 + 3 * kk + (lw - 2));
        ldsrc = data + (size_t)(bb * 24 + row) * TF + 4 * lu;
        if (lw == 1) {
            wdxd.x = W_dx[(4 * lu + 0) * Fn + 4 * lu + 0];
            wdxd.y = W_dx[(4 * lu + 1) * Fn + 4 * lu + 1];
            wdxd.z = W_dx[(4 * lu + 2) * Fn + 4 * lu + 2];
            wdxd.w = W_dx[(4 * lu + 3) * Fn + 4 * lu + 3];
            bdx4.x = b_dx[4 * lu]; bdx4.y = b_dx[4 * lu + 1];
            bdx4.z = b_dx[4 * lu + 2]; bdx4.w = b_dx[4 * lu + 3];
        }
    }
    // feature role (tid<128, lane<36)
    const int fc = tid >> 6, ff = tid & 63;
    const bool isfeat = (tid < 128) && (ff < Fn);
    float* impp = nullptr;
    if (isfeat) {
        int b_ = fc ? bB : bA, k_ = fc ? kB : kA;
        impp = ws + IMP_OFF + (size_t)(k_ * Bn + b_) * TF;
    }

    float creg = 0.f, hreg = 0.f, loss_acc = 0.f;
    __syncthreads();

    // ---- prologue: load t=0..3, stage t=0 (MP parity 0) ----
    float4 cur0 = {0,0,0,0}, cur1 = {0,0,0,0}, cur2 = {0,0,0,0}, cur3 = {0,0,0,0};
    float4 nxt0 = {0,0,0,0}, nxt1 = {0,0,0,0}, nxt2 = {0,0,0,0}, nxt3 = {0,0,0,0};
    if (ldsrc) {
        cur0 = *(const float4*)(ldsrc);
        cur1 = *(const float4*)(ldsrc + Fn);
        cur2 = *(const float4*)(ldsrc + 2 * Fn);
        cur3 = *(const float4*)(ldsrc + 3 * Fn);
        STAGE(cur0, 0);
    }
    __syncthreads();
    if (tid >= 128 && tid < 200) {   // alpha(0)
        int u = tid - 128;
        int c = (u >= 36), f = u - 36 * c;
        float a0 = smf[OFF_BWC + f], a1 = 0.f;
        #pragma unroll
        for (int q = 0; q < 18; ++q) {
            a0 = dot2(smem[OFF_GXP + c * 20 + q], smem[OFF_WWC + q * Fn + f], a0);
            a1 = dot2(smem[OFF_MP + c * 20 + q],  smem[OFF_WWC + (18 + q) * Fn + f], a1);
        }
        smf[OFF_ALPHA + c * Fn + f] = a0 + a1;
    }
    __syncthreads();

    for (int t8 = 0; t8 < Tn; t8 += 4) {
        float iv0 = 0.f, iv1 = 0.f, iv2 = 0.f, iv3 = 0.f;
        float gaccA = 0.f, gaccB = 0.f;
        #pragma unroll
        for (int s = 0; s < 4; ++s) {
            const int t = t8 + s;
            const int par = t & 1, parn = par ^ 1;

            // ======== P3: features (w0-1) | hh (w4-11) | loads (w2-3, s==0) ========
            if (tid < 128) {
                if (ff < Fn) {
                    const int inb = OFF_IN + fc * 180;
                    float m  = smf[inb + ff];
                    float rt = smf[inb + 72 + ff];
                    float a0 = 0.f, a1 = 0.f, a2 = 0.f, a3 = 0.f;
                    #pragma unroll
                    for (int q = 0; q < 64; q += 4) {
                        unsigned int h0 = smem[OFF_HP + fc * 64 + q];
                        unsigned int h1 = smem[OFF_HP + fc * 64 + q + 1];
                        unsigned int h2 = smem[OFF_HP + fc * 64 + q + 2];
                        unsigned int h3 = smem[OFF_HP + fc * 64 + q + 3];
                        a0 = dot2(h0, smem[OFF_WHIST + q * Fn + ff], a0);
                        a1 = dot2(h1, smem[OFF_WHIST + (q + 1) * Fn + ff], a1);
                        a2 = dot2(h2, smem[OFF_WHIST + (q + 2) * Fn + ff], a2);
                        a3 = dot2(h3, smem[OFF_WHIST + (q + 3) * Fn + ff], a3);
                    }
                    float xh = (a0 + a1) + (a2 + a3) + smf[OFF_BH + ff];
                    float xc = m * rt + (1.f - m) * xh;
                    float xcn = __shfl_xor(xc, 1);
                    if (!(ff & 1)) smem[OFF_XCP + fc * 20 + (ff >> 1)] = pkh(xc, xcn);
                    // zh: same-wave round-trip (lgkmcnt only, no barrier)
                    float z0 = 0.f, z1 = 0.f;
                    #pragma unroll
                    for (int q = 0; q < 18; q += 2) {
                        z0 = dot2(smem[OFF_XCP + fc * 20 + q], smem[OFF_WF + q * Fn + ff], z0);
                        z1 = dot2(smem[OFF_XCP + fc * 20 + q + 1], smem[OFF_WF + (q + 1) * Fn + ff], z1);
                    }
                    float zh = z0 + z1 + smf[OFF_BF + ff];
                    float al = smf[OFF_ALPHA + fc * Fn + ff];
                    float chv = al * zh + (1.f - al) * xh;
                    float cc = m * rt + (1.f - m) * chv;
                    loss_acc = fmaf((fabsf(rt - xh) + fabsf(rt - zh) + fabsf(rt - chv)) * m,
                                    smf[OFF_INVD + t], loss_acc);
                    float ccn = __shfl_xor(cc, 1);
                    if (!(ff & 1)) smem[OFF_CCP + fc * 20 + (ff >> 1)] = pkh(cc, ccn);
                    float iv = cc + smf[inb + 144 + ff] + smf[inb + 108 + ff];
                    if (s == 0) iv0 = iv; else if (s == 1) iv1 = iv;
                    else if (s == 2) iv2 = iv; else iv3 = iv;
                }
            } else if (tid < 256) {
                if (s == 0 && ldsrc) {
                    nxt0 = *(const float4*)(ldsrc + (size_t)(t8 + 4) * Fn);
                    nxt1 = *(const float4*)(ldsrc + (size_t)(t8 + 5) * Fn);
                    nxt2 = *(const float4*)(ldsrc + (size_t)(t8 + 6) * Fn);
                    nxt3 = *(const float4*)(ldsrc + (size_t)(t8 + 7) * Fn);
                }
            } else if (tid < 768) {
                const int j = tid - 256;
                float a0 = 0.f, a1 = 0.f, a2 = 0.f, a3 = 0.f;
                float b0 = 0.f, b1 = 0.f, b2 = 0.f, b3 = 0.f;
                #pragma unroll
                for (int kk = 0; kk < 32; kk += 2) {
                    unsigned int ha0 = smem[OFF_HP + 2 * kk];
                    unsigned int ha1 = smem[OFF_HP + 2 * kk + 1];
                    unsigned int ha2 = smem[OFF_HP + 2 * kk + 2];
                    unsigned int ha3 = smem[OFF_HP + 2 * kk + 3];
                    unsigned int hb0 = smem[OFF_HP + 64 + 2 * kk];
                    unsigned int hb1 = smem[OFF_HP + 64 + 2 * kk + 1];
                    unsigned int hb2 = smem[OFF_HP + 64 + 2 * kk + 2];
                    unsigned int hb3 = smem[OFF_HP + 64 + 2 * kk + 3];
                    unsigned int w00 = smem[OFF_WHH + kk * 1024 + j];
                    unsigned int w01 = smem[OFF_WHH + kk * 1024 + 512 + j];
                    unsigned int w10 = smem[OFF_WHH + (kk + 1) * 1024 + j];
                    unsigned int w11 = smem[OFF_WHH + (kk + 1) * 1024 + 512 + j];
                    a0 = dot2(ha0, w00, a0); a1 = dot2(ha1, w01, a1);
                    a2 = dot2(ha2, w10, a2); a3 = dot2(ha3, w11, a3);
                    b0 = dot2(hb0, w00, b0); b1 = dot2(hb1, w01, b1);
                    b2 = dot2(hb2, w10, b2); b3 = dot2(hb3, w11, b3);
                }
                gaccA = (a0 + a1) + (a2 + a3);
                gaccB = (b0 + b1) + (b2 + b3);
            }
            __syncthreads();   // B2

            // ======== P5: gate finalize (hh waves, regs->GF) | stage t+1 (loaders) ========
            if (tid >= 256 && tid < 768) {
                const int j = tid - 256;
                float gA = gaccA + bias_j;
                float gB = gaccB + bias_j;
                DOT18M(gA, OFF_CCP, 0);
                DOT18M(gB, OFF_CCP + 20, 0);
                DOT18M(gA, OFF_MP + par * 40, 18);
                DOT18M(gB, OFF_MP + par * 40 + 20, 18);
                smf[OFF_GFA + j] = gA;
                smf[OFF_GFA + G4 + j] = gB;
            } else if (ldsrc) {
                if (s == 0) STAGE(cur1, parn);
                else if (s == 1) STAGE(cur2, parn);
                else if (s == 2) STAGE(cur3, parn);
                else STAGE(nxt0, parn);
            }
            __syncthreads();   // B3

            // ======== P6: LSTM+decay+hpack (w12-15) | alpha(t+1) (loader waves) ========
            if (tid >= 768) {
                const int idx = tid - 768;
                const int c = idx >> 7, u = idx & 127;
                float ig = smf[OFF_GFA + c * G4 + u];
                float fg = smf[OFF_GFA + c * G4 + 128 + u];
                float gg = smf[OFF_GFA + c * G4 + 256 + u];
                float og = smf[OFF_GFA + c * G4 + 384 + u];
                creg = sigmoid_f(fg) * creg + sigmoid_f(ig) * tanh_f(gg);
                float hn_ = sigmoid_f(og) * tanh_f(creg);
                float g0 = bdh_reg, g1 = 0.f;
                #pragma unroll
                for (int q = 0; q < 18; q += 2) {
                    g0 = dot2(smem[OFF_DP + c * 20 + q], wdh[q], g0);
                    g1 = dot2(smem[OFF_DP + c * 20 + q + 1], wdh[q + 1], g1);
                }
                hreg = hn_ * __expf(-fmaxf(g0 + g1, 0.f));
                float hn2 = __shfl_xor(hreg, 1);
                if (!(u & 1)) smem[OFF_HP + c * 64 + (u >> 1)] = pkh(hreg, hn2);
            } else if (tid >= 128 && tid < 200) {
                int u = tid - 128;
                int c = (u >= 36), f = u - 36 * c;
                float a0 = smf[OFF_BWC + f], a1 = 0.f;
                #pragma unroll
                for (int q = 0; q < 18; ++q) {
                    a0 = dot2(smem[OFF_GXP + c * 20 + q], smem[OFF_WWC + q * Fn + f], a0);
                    a1 = dot2(smem[OFF_MP + parn * 40 + c * 20 + q], smem[OFF_WWC + (18 + q) * Fn + f], a1);
                }
                smf[OFF_ALPHA + c * Fn + f] = a0 + a1;
            }
            __syncthreads();   // B1

            // imp flush once per 4 steps (stores drain under next phases)
            if (s == 3 && isfeat) {
                impp[(size_t)t8 * Fn + ff]       = iv0;
                impp[(size_t)(t8 + 1) * Fn + ff] = iv1;
                impp[(size_t)(t8 + 2) * Fn + ff] = iv2;
                impp[(size_t)(t8 + 3) * Fn + ff] = iv3;
            }
        }
        if (ldsrc) { cur0 = nxt0; cur1 = nxt1; cur2 = nxt2; cur3 = nxt3; }
    }

    // ---- per-block loss partial (fixed order -> deterministic) ----
    __syncthreads();
    if (isfeat) smf[OFF_GFA + fc * Fn + ff] = loss_acc;
    __syncthreads();
    if (tid == 0) {
        float sA = 0.f, sB = 0.f;
        for (int i = 0; i < Fn; ++i) { sA += smf[OFF_GFA + i]; sB += smf[OFF_GFA + Fn + i]; }
        float w0 = W_comb[0], w1 = W_comb[1], w2 = W_comb[2];
        float mx = fmaxf(w0, fmaxf(w1, w2));
        float e0 = expf(w0 - mx), e1 = expf(w1 - mx), e2 = expf(w2 - mx);
        float inv = 1.f / (e0 + e1 + e2);
        float wkA = ((kA == 0) ? e0 : (kA == 1) ? e1 : e2) * inv;
        float wkB = ((kB == 0) ? e0 : (kB == 1) ? e1 : e2) * inv;
        ws[LOSS_OFF + blockIdx.x] = sA * wkA + sB * wkB;
    }
}

// ---------------- k-reduction of imputations ----------------
__global__ void impute_reduce(const float* __restrict__ ws,
                              const float* __restrict__ W_comb,
                              float* __restrict__ out) {
    int idx = blockIdx.x * 256 + threadIdx.x;
    float w0 = W_comb[0], w1 = W_comb[1], w2 = W_comb[2];
    float mx = fmaxf(w0, fmaxf(w1, w2));
    float e0 = expf(w0 - mx), e1 = expf(w1 - mx), e2 = expf(w2 - mx);
    float inv = 1.f / (e0 + e1 + e2);
    const float* imp = ws + IMP_OFF;
    out[1 + idx] = (e0 * imp[idx] + e1 * imp[BTFn + idx] + e2 * imp[2 * BTFn + idx]) * inv;
}

// ---------------- final loss (192 per-block partials) ----------------
__global__ void loss_final(const float* __restrict__ ws,
                           const float* __restrict__ W_comb,
                           float* __restrict__ out) {
    int tid = threadIdx.x;
    __shared__ float red[256];
    const float* lp = ws + LOSS_OFF;
    red[tid] = (tid < 192) ? lp[tid] : 0.f;
    __syncthreads();
    for (int off = 128; off > 0; off >>= 1) {
        if (tid < off) red[tid] += red[tid + off];
        __syncthreads();
    }
    if (tid == 0) {
        float w0 = W_comb[0], w1 = W_comb[1], w2 = W_comb[2];
        float mx = fmaxf(w0, fmaxf(w1, w2));
        float e0 = expf(w0 - mx), e1 = expf(w1 - mx), e2 = expf(w2 - mx);
        float inv = 1.f / (e0 + e1 + e2);
        float wk0 = e0 * inv, wk1 = e1 * inv, wk2 = e2 * inv;
        float reg = 0.1f * (wk0 * (1.f / 24.f) + wk1 * (1.f / 168.f) + wk2 * (1.f / 720.f));
        out[0] = red[0] + (float)Tn * reg;
    }
}

extern "C" void kernel_launch(void* const* d_in, const int* in_sizes, int n_in,
                              void* d_out, int out_size, void* d_ws, size_t ws_size,
                              hipStream_t stream) {
    const float* data   = (const float*)d_in[0];
    const float* W_dh   = (const float*)d_in[1];
    const float* b_dh   = (const float*)d_in[2];
    const float* W_dx   = (const float*)d_in[3];
    const float* b_dx   = (const float*)d_in[4];
    const float* W_hist = (const float*)d_in[5];
    const float* b_hist = (const float*)d_in[6];
    const float* W_feat = (const float*)d_in[7];
    const float* b_feat = (const float*)d_in[8];
    const float* W_wc   = (const float*)d_in[9];
    const float* b_wc   = (const float*)d_in[10];
    const float* W_ih   = (const float*)d_in[11];
    const float* W_hh   = (const float*)d_in[12];
    const float* b_ih   = (const float*)d_in[13];
    const float* b_hh   = (const float*)d_in[14];
    const float* W_comb = (const float*)d_in[15];
    float* ws = (float*)d_ws;
    float* out = (float*)d_out;

    hipLaunchKernelGGL(prep_kernel, dim3(Tn), dim3(256), 0, stream, data, ws);
    hipLaunchKernelGGL(rits_main, dim3(Bn * 3 / 2), dim3(1024), SMEM_WORDS * 4, stream,
                       data, W_dh, b_dh, W_dx, b_dx, W_hist, b_hist,
                       W_feat, b_feat, W_wc, b_wc, W_ih, W_hh, b_ih, b_hh, W_comb, ws);
    hipLaunchKernelGGL(impute_reduce, dim3(BTFn / 256), dim3(256), 0, stream, ws, W_comb, out);
    hipLaunchKernelGGL(loss_final, dim3(1), dim3(256), 0, stream, ws, W_comb, out);
}

// Round 13
// 1145.663 us; speedup vs baseline: 5.4461x; 5.4461x over previous
//
#include <hip/hip_runtime.h>
#include <math.h>

#define Bn 128
#define Tn 256
#define Fn 36
#define Hn 128
#define G4 512
#define BTFn (Bn*Tn*Fn)
#define TF 9216

// ws float offsets
#define INVD_OFF 0
#define LOSS_OFF 102656
#define IMP_OFF  103040

// ---- LDS word offsets (total 8028 words = 31.4 KB -> 2 blocks/CU) ----
#define OFF_WHIST  0      // [q<64][f<36] f16-pairs        : 2304
#define OFF_WF     2304   // [q<18][g<36] diag-zeroed      : 648
#define OFF_WWC    2952   // [q<36][g<36]                  : 1296
#define OFF_WDHT   4248   // [q<18][u<128]                 : 2304
#define OFF_IN     6552   // f32 [w<5][f<36] m,-,rt,tr,se  : 180
#define OFF_DP     6732   // 20
#define OFF_MP     6752   // [par<2][20]                   : 40
#define OFF_GXP    6792   // 20
#define OFF_XCP    6812   // 20
#define OFF_CCP    6832   // 20
#define OFF_ALPHA  6852   // f32 36
#define OFF_HP     6888   // 64 f16-pairs
#define OFF_GF     6952   // f32 512
#define OFF_INVD   7464   // f32 256
#define OFF_BH     7720   // 36
#define OFF_BF     7756   // 36
#define OFF_BWC    7792   // 36
#define OFF_BDH    7828   // f32 128
#define OFF_WDXD   7956   // f32 36
#define OFF_BDX    7992   // f32 36
#define SMEM_WORDS 8028

typedef _Float16 h2_t __attribute__((ext_vector_type(2)));

__device__ __forceinline__ unsigned int bcu(float x) { return __builtin_bit_cast(unsigned int, x); }
__device__ __forceinline__ unsigned int pkh(float a, float b) {
    return __builtin_bit_cast(unsigned int, __builtin_amdgcn_cvt_pkrtz(a, b));
}
__device__ __forceinline__ float dot2(unsigned int a, unsigned int b, float c) {
    return __builtin_amdgcn_fdot2(__builtin_bit_cast(h2_t, a), __builtin_bit_cast(h2_t, b), c, false);
}
__device__ __forceinline__ float sigmoid_f(float x) {
    return __builtin_amdgcn_rcpf(1.f + __expf(-x));
}
__device__ __forceinline__ float tanh_f(float x) {
    return fmaf(2.f, __builtin_amdgcn_rcpf(1.f + __expf(-2.f * x)), -1.f);
}

// ---------------- prep: inv-denom per t ----------------
__global__ void prep_kernel(const float* __restrict__ data,
                            float* __restrict__ ws) {
    int t = blockIdx.x;
    int tid = threadIdx.x;
    __shared__ float red[256];
    float s = 0.f;
    for (int idx = tid; idx < Bn * Fn; idx += 256) {
        int b = idx / Fn, f = idx - b * Fn;
        s += data[((size_t)(b * 24 + 1) * Tn + t) * Fn + f];
    }
    red[tid] = s;
    __syncthreads();
    for (int off = 128; off > 0; off >>= 1) {
        if (tid < off) red[tid] += red[tid + off];
        __syncthreads();
    }
    if (tid == 0) ws[INVD_OFF + t] = 1.f / (red[0] + 1e-5f);
}

// 18 packed dots from LDS base (%4==0) against wi[woff..+17]
#define DOT18(acc, base, woff) do {                                    \
    const unsigned int* _p = &smem[(base)];                            \
    float _a = 0.f, _b = 0.f;                                          \
    float4 _v0 = *(const float4*)_p;                                   \
    _a = dot2(bcu(_v0.x), wi[(woff) + 0], _a);                         \
    _b = dot2(bcu(_v0.y), wi[(woff) + 1], _b);                         \
    _a = dot2(bcu(_v0.z), wi[(woff) + 2], _a);                         \
    _b = dot2(bcu(_v0.w), wi[(woff) + 3], _b);                         \
    float4 _v1 = *(const float4*)(_p + 4);                             \
    _a = dot2(bcu(_v1.x), wi[(woff) + 4], _a);                         \
    _b = dot2(bcu(_v1.y), wi[(woff) + 5], _b);                         \
    _a = dot2(bcu(_v1.z), wi[(woff) + 6], _a);                         \
    _b = dot2(bcu(_v1.w), wi[(woff) + 7], _b);                         \
    float4 _v2 = *(const float4*)(_p + 8);                             \
    _a = dot2(bcu(_v2.x), wi[(woff) + 8], _a);                         \
    _b = dot2(bcu(_v2.y), wi[(woff) + 9], _b);                         \
    _a = dot2(bcu(_v2.z), wi[(woff) + 10], _a);                        \
    _b = dot2(bcu(_v2.w), wi[(woff) + 11], _b);                        \
    float4 _v3 = *(const float4*)(_p + 12);                            \
    _a = dot2(bcu(_v3.x), wi[(woff) + 12], _a);                        \
    _b = dot2(bcu(_v3.y), wi[(woff) + 13], _b);                        \
    _a = dot2(bcu(_v3.z), wi[(woff) + 14], _a);                        \
    _b = dot2(bcu(_v3.w), wi[(woff) + 15], _b);                        \
    float2 _v4 = *(const float2*)(_p + 16);                            \
    _a = dot2(bcu(_v4.x), wi[(woff) + 16], _a);                        \
    _b = dot2(bcu(_v4.y), wi[(woff) + 17], _b);                        \
    acc += _a + _b;                                                    \
} while (0)

// loader staging of one float4 (4 features); P = MP parity for m
#define STAGE(v, P) do {                                                          \
    if (lw == 0) {                                                                \
        *(float4*)&smf[OFF_IN + 4 * lu] = (v);                                    \
        smem[OFF_MP + (P) * 20 + 2 * lu]     = pkh((v).x, (v).y);                 \
        smem[OFF_MP + (P) * 20 + 2 * lu + 1] = pkh((v).z, (v).w);                 \
    } else if (lw == 1) {                                                         \
        smem[OFF_DP + 2 * lu]     = pkh((v).x, (v).y);                            \
        smem[OFF_DP + 2 * lu + 1] = pkh((v).z, (v).w);                            \
        float4 _wd = *(const float4*)&smf[OFF_WDXD + 4 * lu];                     \
        float4 _bd = *(const float4*)&smf[OFF_BDX + 4 * lu];                      \
        float _g0 = __expf(-fmaxf(fmaf((v).x, _wd.x, _bd.x), 0.f));               \
        float _g1 = __expf(-fmaxf(fmaf((v).y, _wd.y, _bd.y), 0.f));               \
        float _g2 = __expf(-fmaxf(fmaf((v).z, _wd.z, _bd.z), 0.f));               \
        float _g3 = __expf(-fmaxf(fmaf((v).w, _wd.w, _bd.w), 0.f));               \
        smem[OFF_GXP + 2 * lu]     = pkh(_g0, _g1);                               \
        smem[OFF_GXP + 2 * lu + 1] = pkh(_g2, _g3);                               \
    } else {                                                                      \
        *(float4*)&smf[OFF_IN + lw * 36 + 4 * lu] = (v);                          \
    }                                                                             \
} while (0)

// ---------------- main: 384 blocks x 512 threads, 1 chain/block, 2 blocks/CU ----------------
__global__ __launch_bounds__(512) void rits_main(
    const float* __restrict__ data,
    const float* __restrict__ W_dh, const float* __restrict__ b_dh,
    const float* __restrict__ W_dx, const float* __restrict__ b_dx,
    const float* __restrict__ W_hist, const float* __restrict__ b_hist,
    const float* __restrict__ W_feat, const float* __restrict__ b_feat,
    const float* __restrict__ W_wc, const float* __restrict__ b_wc,
    const float* __restrict__ W_ih, const float* __restrict__ W_hh,
    const float* __restrict__ b_ih, const float* __restrict__ b_hh,
    const float* __restrict__ W_comb,
    float* __restrict__ ws) {

    extern __shared__ unsigned int smem[];
    float* smf = (float*)smem;

    const int tid = threadIdx.x;
    const int chain = blockIdx.x;
    const int b = chain / 3, k = chain - 3 * b;

    // ---- one-time LDS staging (small matrices only) ----
    for (int i = tid; i < 64 * Fn; i += 512) {
        int q = i / Fn, f = i - q * Fn;
        float2 wv = *(const float2*)&W_hist[f * Hn + 2 * q];
        smem[OFF_WHIST + i] = pkh(wv.x, wv.y);
    }
    for (int i = tid; i < 18 * Fn; i += 512) {
        int q = i / Fn, g = i - q * Fn;
        float2 wv = *(const float2*)&W_feat[g * Fn + 2 * q];
        float w0 = (2 * q     == g) ? 0.f : wv.x;
        float w1 = (2 * q + 1 == g) ? 0.f : wv.y;
        smem[OFF_WF + i] = pkh(w0, w1);
    }
    for (int i = tid; i < 36 * Fn; i += 512) {
        int q = i / Fn, g = i - q * Fn;
        int col = (q < 18) ? 2 * q : Fn + 2 * (q - 18);
        float2 wv = *(const float2*)&W_wc[g * 2 * Fn + col];
        smem[OFF_WWC + i] = pkh(wv.x, wv.y);
    }
    for (int i = tid; i < 18 * 128; i += 512) {
        int q = i >> 7, u = i & 127;
        float2 wv = *(const float2*)&W_dh[u * Fn + 2 * q];
        smem[OFF_WDHT + i] = pkh(wv.x, wv.y);
    }
    if (tid < Fn) {
        smf[OFF_BH + tid]   = b_hist[tid];
        smf[OFF_BF + tid]   = b_feat[tid];
        smf[OFF_BWC + tid]  = b_wc[tid];
        smf[OFF_WDXD + tid] = W_dx[tid * Fn + tid];
        smf[OFF_BDX + tid]  = b_dx[tid];
    }
    if (tid < Hn) smf[OFF_BDH + tid] = b_dh[tid];
    for (int i = tid; i < Tn; i += 512) smf[OFF_INVD + i] = ws[INVD_OFF + i];
    if (tid < 64) smem[OFF_HP + tid] = 0;

    // ---- per-thread gate-row registers: W_hh row (64 u32) + W_ih row (36 u32) ----
    unsigned int wh[64];
    #pragma unroll
    for (int q = 0; q < 64; ++q) {
        float2 wv = *(const float2*)&W_hh[tid * Hn + 2 * q];
        wh[q] = pkh(wv.x, wv.y);
    }
    unsigned int wi[36];
    #pragma unroll
    for (int q = 0; q < 36; ++q) {
        float2 wv = *(const float2*)&W_ih[tid * 2 * Fn + 2 * q];
        wi[q] = pkh(wv.x, wv.y);
    }
    const float bias_j = b_ih[tid] + b_hh[tid];

    // ---- loader role: tid in [64,109), 45 threads x float4 over 5 rows ----
    const float* ldsrc = nullptr; int lw = 0, lu = 0;
    if (tid >= 64 && tid < 109) {
        int idx = tid - 64;
        lw = idx / 9; lu = idx - 9 * lw;
        int row = (lw == 0) ? 1 : (lw == 1) ? 2 : (3 + 3 * k + (lw - 2));
        ldsrc = data + (size_t)(b * 24 + row) * TF + 4 * lu;
    }
    // ---- feature role: tid<36 ----
    float* impp = ws + IMP_OFF + (size_t)(k * Bn + b) * TF;

    float creg = 0.f, hreg = 0.f, loss_acc = 0.f;
    __syncthreads();

    // ---- prologue: stage t=0 (MP parity 0), then alpha(0) ----
    if (ldsrc) {
        float4 v0 = *(const float4*)(ldsrc);
        STAGE(v0, 0);
    }
    __syncthreads();
    if (tid >= 128 && tid < 164) {
        int f = tid - 128;
        float a0 = smf[OFF_BWC + f], a1 = 0.f;
        #pragma unroll
        for (int q = 0; q < 18; ++q) {
            a0 = dot2(smem[OFF_GXP + q], smem[OFF_WWC + q * Fn + f], a0);
            a1 = dot2(smem[OFF_MP + q],  smem[OFF_WWC + (18 + q) * Fn + f], a1);
        }
        smf[OFF_ALPHA + f] = a0 + a1;
    }
    __syncthreads();

    for (int t = 0; t < Tn; ++t) {
        const int par = t & 1, parn = par ^ 1;

        // ======== P_A: hh-dot (all, row j from regs) | features (tid<36) | load t+1 ========
        float4 nxt = {0, 0, 0, 0};
        if (ldsrc) nxt = *(const float4*)(ldsrc + (size_t)(t + 1) * Fn);  // t=255: in-bounds, unused

        float gacc;
        {
            float g0 = 0.f, g1 = 0.f, g2 = 0.f, g3 = 0.f;
            #pragma unroll
            for (int q = 0; q < 64; q += 4) {
                float4 hp = *(const float4*)&smem[OFF_HP + q];
                g0 = dot2(bcu(hp.x), wh[q],     g0);
                g1 = dot2(bcu(hp.y), wh[q + 1], g1);
                g2 = dot2(bcu(hp.z), wh[q + 2], g2);
                g3 = dot2(bcu(hp.w), wh[q + 3], g3);
            }
            gacc = (g0 + g1) + (g2 + g3);
        }
        if (tid < Fn) {
            float m  = smf[OFF_IN + tid];
            float rt = smf[OFF_IN + 72 + tid];
            float a0 = 0.f, a1 = 0.f, a2 = 0.f, a3 = 0.f;
            #pragma unroll
            for (int q = 0; q < 64; q += 4) {
                unsigned int h0 = smem[OFF_HP + q];
                unsigned int h1 = smem[OFF_HP + q + 1];
                unsigned int h2 = smem[OFF_HP + q + 2];
                unsigned int h3 = smem[OFF_HP + q + 3];
                a0 = dot2(h0, smem[OFF_WHIST + q * Fn + tid], a0);
                a1 = dot2(h1, smem[OFF_WHIST + (q + 1) * Fn + tid], a1);
                a2 = dot2(h2, smem[OFF_WHIST + (q + 2) * Fn + tid], a2);
                a3 = dot2(h3, smem[OFF_WHIST + (q + 3) * Fn + tid], a3);
            }
            float xh = (a0 + a1) + (a2 + a3) + smf[OFF_BH + tid];
            float xc = m * rt + (1.f - m) * xh;
            float xcn = __shfl_xor(xc, 1);
            if (!(tid & 1)) smem[OFF_XCP + (tid >> 1)] = pkh(xc, xcn);
            // zh: same-wave LDS round-trip (wave-ordered, no barrier)
            float z0 = 0.f, z1 = 0.f;
            #pragma unroll
            for (int q = 0; q < 18; q += 2) {
                z0 = dot2(smem[OFF_XCP + q], smem[OFF_WF + q * Fn + tid], z0);
                z1 = dot2(smem[OFF_XCP + q + 1], smem[OFF_WF + (q + 1) * Fn + tid], z1);
            }
            float zh = z0 + z1 + smf[OFF_BF + tid];
            float al = smf[OFF_ALPHA + tid];
            float chv = al * zh + (1.f - al) * xh;
            float cc = m * rt + (1.f - m) * chv;
            loss_acc = fmaf((fabsf(rt - xh) + fabsf(rt - zh) + fabsf(rt - chv)) * m,
                            smf[OFF_INVD + t], loss_acc);
            float ccn = __shfl_xor(cc, 1);
            if (!(tid & 1)) smem[OFF_CCP + (tid >> 1)] = pkh(cc, ccn);
            impp[(size_t)t * Fn + tid] = cc + smf[OFF_IN + 144 + tid] + smf[OFF_IN + 108 + tid];
        }
        __syncthreads();   // B2

        // ======== P_B: gate finalize (all rows) | stage t+1 (loaders) ========
        {
            float gA = gacc + bias_j;
            DOT18(gA, OFF_CCP, 0);
            DOT18(gA, OFF_MP + par * 20, 18);
            smf[OFF_GF + tid] = gA;
        }
        if (ldsrc) STAGE(nxt, parn);
        __syncthreads();   // B3

        // ======== P_C: LSTM + decay(t+1) + h-pack (tid<128) | alpha(t+1) (128..163) ========
        if (tid < Hn) {
            float ig = smf[OFF_GF + tid];
            float fg = smf[OFF_GF + 128 + tid];
            float gg = smf[OFF_GF + 256 + tid];
            float og = smf[OFF_GF + 384 + tid];
            creg = sigmoid_f(fg) * creg + sigmoid_f(ig) * tanh_f(gg);
            float hn_ = sigmoid_f(og) * tanh_f(creg);
            float g0 = smf[OFF_BDH + tid], g1 = 0.f;
            #pragma unroll
            for (int q = 0; q < 18; q += 2) {
                g0 = dot2(smem[OFF_DP + q], smem[OFF_WDHT + q * 128 + tid], g0);
                g1 = dot2(smem[OFF_DP + q + 1], smem[OFF_WDHT + (q + 1) * 128 + tid], g1);
            }
            hreg = hn_ * __expf(-fmaxf(g0 + g1, 0.f));
            float hn2 = __shfl_xor(hreg, 1);
            if (!(tid & 1)) smem[OFF_HP + (tid >> 1)] = pkh(hreg, hn2);
        } else if (tid < 164) {
            int f = tid - 128;
            float a0 = smf[OFF_BWC + f], a1 = 0.f;
            #pragma unroll
            for (int q = 0; q < 18; ++q) {
                a0 = dot2(smem[OFF_GXP + q], smem[OFF_WWC + q * Fn + f], a0);
                a1 = dot2(smem[OFF_MP + parn * 20 + q], smem[OFF_WWC + (18 + q) * Fn + f], a1);
            }
            smf[OFF_ALPHA + f] = a0 + a1;
        }
        __syncthreads();   // B1
    }

    // ---- loss partial (fixed order -> deterministic) ----
    if (tid < Fn) smf[OFF_GF + tid] = loss_acc;
    __syncthreads();
    if (tid == 0) {
        float s = 0.f;
        for (int i = 0; i < Fn; ++i) s += smf[OFF_GF + i];
        float w0 = W_comb[0], w1 = W_comb[1], w2 = W_comb[2];
        float mx = fmaxf(w0, fmaxf(w1, w2));
        float e0 = expf(w0 - mx), e1 = expf(w1 - mx), e2 = expf(w2 - mx);
        float wkk = ((k == 0) ? e0 : (k == 1) ? e1 : e2) / (e0 + e1 + e2);
        ws[LOSS_OFF + chain] = s * wkk;
    }
}

// ---------------- k-reduction of imputations ----------------
__global__ void impute_reduce(const float* __restrict__ ws,
                              const float* __restrict__ W_comb,
                              float* __restrict__ out) {
    int idx = blockIdx.x * 256 + threadIdx.x;
    float w0 = W_comb[0], w1 = W_comb[1], w2 = W_comb[2];
    float mx = fmaxf(w0, fmaxf(w1, w2));
    float e0 = expf(w0 - mx), e1 = expf(w1 - mx), e2 = expf(w2 - mx);
    float inv = 1.f / (e0 + e1 + e2);
    const float* imp = ws + IMP_OFF;
    out[1 + idx] = (e0 * imp[idx] + e1 * imp[BTFn + idx] + e2 * imp[2 * BTFn + idx]) * inv;
}

// ---------------- final loss (384 per-chain partials) ----------------
__global__ void loss_final(const float* __restrict__ ws,
                           const float* __restrict__ W_comb,
                           float* __restrict__ out) {
    int tid = threadIdx.x;
    __shared__ float red[512];
    const float* lp = ws + LOSS_OFF;
    red[tid] = (tid < 384) ? lp[tid] : 0.f;
    __syncthreads();
    for (int off = 256; off > 0; off >>= 1) {
        if (tid < off) red[tid] += red[tid + off];
        __syncthreads();
    }
    if (tid == 0) {
        float w0 = W_comb[0], w1 = W_comb[1], w2 = W_comb[2];
        float mx = fmaxf(w0, fmaxf(w1, w2));
        float e0 = expf(w0 - mx), e1 = expf(w1 - mx), e2 = expf(w2 - mx);
        float inv = 1.f / (e0 + e1 + e2);
        float wk0 = e0 * inv, wk1 = e1 * inv, wk2 = e2 * inv;
        float reg = 0.1f * (wk0 * (1.f / 24.f) + wk1 * (1.f / 168.f) + wk2 * (1.f / 720.f));
        out[0] = red[0] + (float)Tn * reg;
    }
}

extern "C" void kernel_launch(void* const* d_in, const int* in_sizes, int n_in,
                              void* d_out, int out_size, void* d_ws, size_t ws_size,
                              hipStream_t stream) {
    const float* data   = (const float*)d_in[0];
    const float* W_dh   = (const float*)d_in[1];
    const float* b_dh   = (const float*)d_in[2];
    const float* W_dx   = (const float*)d_in[3];
    const float* b_dx   = (const float*)d_in[4];
    const float* W_hist = (const float*)d_in[5];
    const float* b_hist = (const float*)d_in[6];
    const float* W_feat = (const float*)d_in[7];
    const float* b_feat = (const float*)d_in[8];
    const float* W_wc   = (const float*)d_in[9];
    const float* b_wc   = (const float*)d_in[10];
    const float* W_ih   = (const float*)d_in[11];
    const float* W_hh   = (const float*)d_in[12];
    const float* b_ih   = (const float*)d_in[13];
    const float* b_hh   = (const float*)d_in[14];
    const float* W_comb = (const float*)d_in[15];
    float* ws = (float*)d_ws;
    float* out = (float*)d_out;

    hipLaunchKernelGGL(prep_kernel, dim3(Tn), dim3(256), 0, stream, data, ws);
    hipLaunchKernelGGL(rits_main, dim3(Bn * 3), dim3(512), SMEM_WORDS * 4, stream,
                       data, W_dh, b_dh, W_dx, b_dx, W_hist, b_hist,
                       W_feat, b_feat, W_wc, b_wc, W_ih, W_hh, b_ih, b_hh, W_comb, ws);
    hipLaunchKernelGGL(impute_reduce, dim3(BTFn / 256), dim3(256), 0, stream, ws, W_comb, out);
    hipLaunchKernelGGL(loss_final, dim3(1), dim3(512), 0, stream, ws, W_comb, out);
}

// Round 14
// 1015.508 us; speedup vs baseline: 6.1441x; 1.1282x over previous
//
#include <hip/hip_runtime.h>
#include <math.h>

#define Bn 128
#define Tn 256
#define Fn 36
#define Hn 128
#define G4 512
#define BTFn (Bn*Tn*Fn)
#define TF 9216

// ws float offsets
#define INVD_OFF 0
#define LOSS_OFF 102656
#define IMP_OFF  103040

// ---- LDS word offsets (total 8028 words = 31.4 KB -> 2 blocks/CU) ----
#define OFF_WHIST  0      // [q<64][f<36] f16-pairs        : 2304
#define OFF_WF     2304   // [q<18][g<36] diag-zeroed      : 648
#define OFF_WWC    2952   // [q<36][g<36]                  : 1296
#define OFF_WDHT   4248   // [q<18][u<128]                 : 2304
#define OFF_IN     6552   // f32 [w<5][f<36] m,-,rt,tr,se  : 180
#define OFF_DP     6732   // 20
#define OFF_MP     6752   // [par<2][20]                   : 40
#define OFF_GXP    6792   // 20
#define OFF_XCP    6812   // 20
#define OFF_CCP    6832   // 20
#define OFF_ALPHA  6852   // f32 36
#define OFF_HP     6888   // 64 f16-pairs
#define OFF_GF     6952   // f32 512
#define OFF_INVD   7464   // f32 256
#define OFF_BH     7720   // 36
#define OFF_BF     7756   // 36
#define OFF_BWC    7792   // 36
#define OFF_BDH    7828   // f32 128
#define OFF_WDXD   7956   // f32 36
#define OFF_BDX    7992   // f32 36
#define SMEM_WORDS 8028

typedef _Float16 h2_t __attribute__((ext_vector_type(2)));

__device__ __forceinline__ unsigned int bcu(float x) { return __builtin_bit_cast(unsigned int, x); }
__device__ __forceinline__ unsigned int pkh(float a, float b) {
    return __builtin_bit_cast(unsigned int, __builtin_amdgcn_cvt_pkrtz(a, b));
}
__device__ __forceinline__ float dot2(unsigned int a, unsigned int b, float c) {
    return __builtin_amdgcn_fdot2(__builtin_bit_cast(h2_t, a), __builtin_bit_cast(h2_t, b), c, false);
}
__device__ __forceinline__ float sigmoid_f(float x) {
    return __builtin_amdgcn_rcpf(1.f + __expf(-x));
}
__device__ __forceinline__ float tanh_f(float x) {
    return fmaf(2.f, __builtin_amdgcn_rcpf(1.f + __expf(-2.f * x)), -1.f);
}

// ---------------- prep: inv-denom per t ----------------
__global__ void prep_kernel(const float* __restrict__ data,
                            float* __restrict__ ws) {
    int t = blockIdx.x;
    int tid = threadIdx.x;
    __shared__ float red[256];
    float s = 0.f;
    for (int idx = tid; idx < Bn * Fn; idx += 256) {
        int b = idx / Fn, f = idx - b * Fn;
        s += data[((size_t)(b * 24 + 1) * Tn + t) * Fn + f];
    }
    red[tid] = s;
    __syncthreads();
    for (int off = 128; off > 0; off >>= 1) {
        if (tid < off) red[tid] += red[tid + off];
        __syncthreads();
    }
    if (tid == 0) ws[INVD_OFF + t] = 1.f / (red[0] + 1e-5f);
}

// 18 packed dots from LDS base (%4==0) against wi[woff..+17]
#define DOT18(acc, base, woff) do {                                    \
    const unsigned int* _p = &smem[(base)];                            \
    float _a = 0.f, _b = 0.f;                                          \
    float4 _v0 = *(const float4*)_p;                                   \
    _a = dot2(bcu(_v0.x), wi[(woff) + 0], _a);                         \
    _b = dot2(bcu(_v0.y), wi[(woff) + 1], _b);                         \
    _a = dot2(bcu(_v0.z), wi[(woff) + 2], _a);                         \
    _b = dot2(bcu(_v0.w), wi[(woff) + 3], _b);                         \
    float4 _v1 = *(const float4*)(_p + 4);                             \
    _a = dot2(bcu(_v1.x), wi[(woff) + 4], _a);                         \
    _b = dot2(bcu(_v1.y), wi[(woff) + 5], _b);                         \
    _a = dot2(bcu(_v1.z), wi[(woff) + 6], _a);                         \
    _b = dot2(bcu(_v1.w), wi[(woff) + 7], _b);                         \
    float4 _v2 = *(const float4*)(_p + 8);                             \
    _a = dot2(bcu(_v2.x), wi[(woff) + 8], _a);                         \
    _b = dot2(bcu(_v2.y), wi[(woff) + 9], _b);                         \
    _a = dot2(bcu(_v2.z), wi[(woff) + 10], _a);                        \
    _b = dot2(bcu(_v2.w), wi[(woff) + 11], _b);                        \
    float4 _v3 = *(const float4*)(_p + 12);                            \
    _a = dot2(bcu(_v3.x), wi[(woff) + 12], _a);                        \
    _b = dot2(bcu(_v3.y), wi[(woff) + 13], _b);                        \
    _a = dot2(bcu(_v3.z), wi[(woff) + 14], _a);                        \
    _b = dot2(bcu(_v3.w), wi[(woff) + 15], _b);                        \
    float2 _v4 = *(const float2*)(_p + 16);                            \
    _a = dot2(bcu(_v4.x), wi[(woff) + 16], _a);                        \
    _b = dot2(bcu(_v4.y), wi[(woff) + 17], _b);                        \
    acc += _a + _b;                                                    \
} while (0)

// loader staging of one float2 (2 features); P = MP parity for m
#define STAGE(v, P) do {                                                          \
    if (lw == 0) {                                                                \
        *(float2*)&smf[OFF_IN + 2 * lu] = (v);                                    \
        smem[OFF_MP + (P) * 20 + lu] = pkh((v).x, (v).y);                         \
    } else if (lw == 1) {                                                         \
        smem[OFF_DP + lu] = pkh((v).x, (v).y);                                    \
        float2 _wd = *(const float2*)&smf[OFF_WDXD + 2 * lu];                     \
        float2 _bd = *(const float2*)&smf[OFF_BDX + 2 * lu];                      \
        float _g0 = __expf(-fmaxf(fmaf((v).x, _wd.x, _bd.x), 0.f));               \
        float _g1 = __expf(-fmaxf(fmaf((v).y, _wd.y, _bd.y), 0.f));               \
        smem[OFF_GXP + lu] = pkh(_g0, _g1);                                       \
    } else {                                                                      \
        *(float2*)&smf[OFF_IN + lw * 36 + 2 * lu] = (v);                          \
    }                                                                             \
} while (0)

// ---------------- main: 384 blocks x 512 threads, 1 chain/block, 2 blocks/CU ----------------
__global__ __launch_bounds__(512) void rits_main(
    const float* __restrict__ data,
    const float* __restrict__ W_dh, const float* __restrict__ b_dh,
    const float* __restrict__ W_dx, const float* __restrict__ b_dx,
    const float* __restrict__ W_hist, const float* __restrict__ b_hist,
    const float* __restrict__ W_feat, const float* __restrict__ b_feat,
    const float* __restrict__ W_wc, const float* __restrict__ b_wc,
    const float* __restrict__ W_ih, const float* __restrict__ W_hh,
    const float* __restrict__ b_ih, const float* __restrict__ b_hh,
    const float* __restrict__ W_comb,
    float* __restrict__ ws) {

    extern __shared__ unsigned int smem[];
    float* smf = (float*)smem;

    const int tid = threadIdx.x;
    const int chain = blockIdx.x;
    const int b = chain / 3, k = chain - 3 * b;

    // ---- one-time LDS staging (small matrices only) ----
    for (int i = tid; i < 64 * Fn; i += 512) {
        int q = i / Fn, f = i - q * Fn;
        float2 wv = *(const float2*)&W_hist[f * Hn + 2 * q];
        smem[OFF_WHIST + i] = pkh(wv.x, wv.y);
    }
    for (int i = tid; i < 18 * Fn; i += 512) {
        int q = i / Fn, g = i - q * Fn;
        float2 wv = *(const float2*)&W_feat[g * Fn + 2 * q];
        float w0 = (2 * q     == g) ? 0.f : wv.x;
        float w1 = (2 * q + 1 == g) ? 0.f : wv.y;
        smem[OFF_WF + i] = pkh(w0, w1);
    }
    for (int i = tid; i < 36 * Fn; i += 512) {
        int q = i / Fn, g = i - q * Fn;
        int col = (q < 18) ? 2 * q : Fn + 2 * (q - 18);
        float2 wv = *(const float2*)&W_wc[g * 2 * Fn + col];
        smem[OFF_WWC + i] = pkh(wv.x, wv.y);
    }
    for (int i = tid; i < 18 * 128; i += 512) {
        int q = i >> 7, u = i & 127;
        float2 wv = *(const float2*)&W_dh[u * Fn + 2 * q];
        smem[OFF_WDHT + i] = pkh(wv.x, wv.y);
    }
    if (tid < Fn) {
        smf[OFF_BH + tid]   = b_hist[tid];
        smf[OFF_BF + tid]   = b_feat[tid];
        smf[OFF_BWC + tid]  = b_wc[tid];
        smf[OFF_WDXD + tid] = W_dx[tid * Fn + tid];
        smf[OFF_BDX + tid]  = b_dx[tid];
    }
    if (tid < Hn) smf[OFF_BDH + tid] = b_dh[tid];
    for (int i = tid; i < Tn; i += 512) smf[OFF_INVD + i] = ws[INVD_OFF + i];
    if (tid < 64) smem[OFF_HP + tid] = 0;

    // ---- per-thread gate-row registers: W_hh row (64 u32) + W_ih row (36 u32) ----
    unsigned int wh[64];
    #pragma unroll
    for (int q = 0; q < 64; ++q) {
        float2 wv = *(const float2*)&W_hh[tid * Hn + 2 * q];
        wh[q] = pkh(wv.x, wv.y);
    }
    unsigned int wi[36];
    #pragma unroll
    for (int q = 0; q < 36; ++q) {
        float2 wv = *(const float2*)&W_ih[tid * 2 * Fn + 2 * q];
        wi[q] = pkh(wv.x, wv.y);
    }
    const float bias_j = b_ih[tid] + b_hh[tid];

    // ---- loader role: tid in [64,154), 90 threads x float2 over 5 rows ----
    const float* ldsrc = nullptr; int lw = 0, lu = 0;
    if (tid >= 64 && tid < 154) {
        int idx = tid - 64;
        lw = idx / 18; lu = idx - 18 * lw;
        int row = (lw == 0) ? 1 : (lw == 1) ? 2 : (3 + 3 * k + (lw - 2));
        ldsrc = data + (size_t)(b * 24 + row) * TF + 2 * lu;
    }
    // ---- feature role: tid<36 ----
    float* impp = ws + IMP_OFF + (size_t)(k * Bn + b) * TF;

    float creg = 0.f, hreg = 0.f, loss_acc = 0.f, gm = 0.f;
    __syncthreads();

    // ---- prologue: load t=0..3, stage t=0 (MP parity 0); then alpha(0)+gm(0) ----
    float2 cur1 = {0,0}, cur2 = {0,0}, cur3 = {0,0};
    float2 nxt0 = {0,0}, nxt1 = {0,0}, nxt2 = {0,0}, nxt3 = {0,0};
    if (ldsrc) {
        float2 c0 = *(const float2*)(ldsrc);
        cur1 = *(const float2*)(ldsrc + Fn);
        cur2 = *(const float2*)(ldsrc + 2 * Fn);
        cur3 = *(const float2*)(ldsrc + 3 * Fn);
        STAGE(c0, 0);
    }
    __syncthreads();
    if (tid >= 128 && tid < 164) {
        int f = tid - 128;
        float a0 = smf[OFF_BWC + f], a1 = 0.f;
        #pragma unroll
        for (int q = 0; q < 18; ++q) {
            a0 = dot2(smem[OFF_GXP + q], smem[OFF_WWC + q * Fn + f], a0);
            a1 = dot2(smem[OFF_MP + q],  smem[OFF_WWC + (18 + q) * Fn + f], a1);
        }
        smf[OFF_ALPHA + f] = a0 + a1;
    }
    DOT18(gm, OFF_MP, 18);       // gm(0), MP parity 0
    __syncthreads();

    for (int t8 = 0; t8 < Tn; t8 += 4) {
        float iv0 = 0.f, iv1 = 0.f, iv2 = 0.f, iv3 = 0.f;
        #pragma unroll
        for (int s = 0; s < 4; ++s) {
            const int t = t8 + s;
            const int par = s & 1, parn = par ^ 1;   // t8 even -> t parity == s parity

            // ======== P_A: hh-dot (all) | features (tid<36) | batched loads (s==0) ========
            if (s == 0 && ldsrc) {
                nxt0 = *(const float2*)(ldsrc + (size_t)(t8 + 4) * Fn);
                nxt1 = *(const float2*)(ldsrc + (size_t)(t8 + 5) * Fn);
                nxt2 = *(const float2*)(ldsrc + (size_t)(t8 + 6) * Fn);
                nxt3 = *(const float2*)(ldsrc + (size_t)(t8 + 7) * Fn);
            }
            float gacc;
            {
                float g0 = 0.f, g1 = 0.f, g2 = 0.f, g3 = 0.f;
                #pragma unroll
                for (int q = 0; q < 64; q += 4) {
                    float4 hp = *(const float4*)&smem[OFF_HP + q];
                    g0 = dot2(bcu(hp.x), wh[q],     g0);
                    g1 = dot2(bcu(hp.y), wh[q + 1], g1);
                    g2 = dot2(bcu(hp.z), wh[q + 2], g2);
                    g3 = dot2(bcu(hp.w), wh[q + 3], g3);
                }
                gacc = (g0 + g1) + (g2 + g3);
            }
            if (tid < Fn) {
                float m  = smf[OFF_IN + tid];
                float rt = smf[OFF_IN + 72 + tid];
                float a0 = 0.f, a1 = 0.f, a2 = 0.f, a3 = 0.f;
                #pragma unroll
                for (int q = 0; q < 64; q += 4) {
                    unsigned int h0 = smem[OFF_HP + q];
                    unsigned int h1 = smem[OFF_HP + q + 1];
                    unsigned int h2 = smem[OFF_HP + q + 2];
                    unsigned int h3 = smem[OFF_HP + q + 3];
                    a0 = dot2(h0, smem[OFF_WHIST + q * Fn + tid], a0);
                    a1 = dot2(h1, smem[OFF_WHIST + (q + 1) * Fn + tid], a1);
                    a2 = dot2(h2, smem[OFF_WHIST + (q + 2) * Fn + tid], a2);
                    a3 = dot2(h3, smem[OFF_WHIST + (q + 3) * Fn + tid], a3);
                }
                float xh = (a0 + a1) + (a2 + a3) + smf[OFF_BH + tid];
                float xc = m * rt + (1.f - m) * xh;
                float xcn = __shfl_xor(xc, 1);
                if (!(tid & 1)) smem[OFF_XCP + (tid >> 1)] = pkh(xc, xcn);
                // zh: same-wave LDS round-trip (wave-ordered, no barrier)
                float z0 = 0.f, z1 = 0.f;
                #pragma unroll
                for (int q = 0; q < 18; q += 2) {
                    z0 = dot2(smem[OFF_XCP + q], smem[OFF_WF + q * Fn + tid], z0);
                    z1 = dot2(smem[OFF_XCP + q + 1], smem[OFF_WF + (q + 1) * Fn + tid], z1);
                }
                float zh = z0 + z1 + smf[OFF_BF + tid];
                float al = smf[OFF_ALPHA + tid];
                float chv = al * zh + (1.f - al) * xh;
                float cc = m * rt + (1.f - m) * chv;
                loss_acc = fmaf((fabsf(rt - xh) + fabsf(rt - zh) + fabsf(rt - chv)) * m,
                                smf[OFF_INVD + t], loss_acc);
                float ccn = __shfl_xor(cc, 1);
                if (!(tid & 1)) smem[OFF_CCP + (tid >> 1)] = pkh(cc, ccn);
                float iv = cc + smf[OFF_IN + 144 + tid] + smf[OFF_IN + 108 + tid];
                if (s == 0) iv0 = iv; else if (s == 1) iv1 = iv;
                else if (s == 2) iv2 = iv; else iv3 = iv;
            }
            __syncthreads();   // B2

            // ======== P_B: gate finalize (cc-part only) | stage t+1 (loaders) ========
            {
                float gA = gacc + gm + bias_j;
                DOT18(gA, OFF_CCP, 0);
                smf[OFF_GF + tid] = gA;
            }
            if (ldsrc) {
                if (s == 0) STAGE(cur1, parn);
                else if (s == 1) STAGE(cur2, parn);
                else if (s == 2) STAGE(cur3, parn);
                else STAGE(nxt0, parn);
            }
            __syncthreads();   // B3

            // ======== P_C: LSTM+decay+hpack (tid<128) | alpha(t+1) (128..163) | gm(t+1) all ========
            if (tid < Hn) {
                float ig = smf[OFF_GF + tid];
                float fg = smf[OFF_GF + 128 + tid];
                float gg = smf[OFF_GF + 256 + tid];
                float og = smf[OFF_GF + 384 + tid];
                creg = sigmoid_f(fg) * creg + sigmoid_f(ig) * tanh_f(gg);
                float hn_ = sigmoid_f(og) * tanh_f(creg);
                float g0 = smf[OFF_BDH + tid], g1 = 0.f;
                #pragma unroll
                for (int q = 0; q < 18; q += 2) {
                    g0 = dot2(smem[OFF_DP + q], smem[OFF_WDHT + q * 128 + tid], g0);
                    g1 = dot2(smem[OFF_DP + q + 1], smem[OFF_WDHT + (q + 1) * 128 + tid], g1);
                }
                hreg = hn_ * __expf(-fmaxf(g0 + g1, 0.f));
                float hn2 = __shfl_xor(hreg, 1);
                if (!(tid & 1)) smem[OFF_HP + (tid >> 1)] = pkh(hreg, hn2);
            } else if (tid < 164) {
                int f = tid - 128;
                float a0 = smf[OFF_BWC + f], a1 = 0.f;
                #pragma unroll
                for (int q = 0; q < 18; ++q) {
                    a0 = dot2(smem[OFF_GXP + q], smem[OFF_WWC + q * Fn + f], a0);
                    a1 = dot2(smem[OFF_MP + parn * 20 + q], smem[OFF_WWC + (18 + q) * Fn + f], a1);
                }
                smf[OFF_ALPHA + f] = a0 + a1;
            }
            gm = 0.f;
            DOT18(gm, OFF_MP + parn * 20, 18);   // m(t+1), staged in P_B
            __syncthreads();   // B1

            // imp flush once per 4 steps; stores drain under next group's P_A->B2
            if (s == 3 && tid < Fn) {
                impp[(size_t)t8 * Fn + tid]       = iv0;
                impp[(size_t)(t8 + 1) * Fn + tid] = iv1;
                impp[(size_t)(t8 + 2) * Fn + tid] = iv2;
                impp[(size_t)(t8 + 3) * Fn + tid] = iv3;
            }
        }
        if (ldsrc) { cur1 = nxt1; cur2 = nxt2; cur3 = nxt3; }
    }

    // ---- loss partial (fixed order -> deterministic) ----
    if (tid < Fn) smf[OFF_GF + tid] = loss_acc;
    __syncthreads();
    if (tid == 0) {
        float s = 0.f;
        for (int i = 0; i < Fn; ++i) s += smf[OFF_GF + i];
        float w0 = W_comb[0], w1 = W_comb[1], w2 = W_comb[2];
        float mx = fmaxf(w0, fmaxf(w1, w2));
        float e0 = expf(w0 - mx), e1 = expf(w1 - mx), e2 = expf(w2 - mx);
        float wkk = ((k == 0) ? e0 : (k == 1) ? e1 : e2) / (e0 + e1 + e2);
        ws[LOSS_OFF + chain] = s * wkk;
    }
}

// ---------------- k-reduction of imputations ----------------
__global__ void impute_reduce(const float* __restrict__ ws,
                              const float* __restrict__ W_comb,
                              float* __restrict__ out) {
    int idx = blockIdx.x * 256 + threadIdx.x;
    float w0 = W_comb[0], w1 = W_comb[1], w2 = W_comb[2];
    float mx = fmaxf(w0, fmaxf(w1, w2));
    float e0 = expf(w0 - mx), e1 = expf(w1 - mx), e2 = expf(w2 - mx);
    float inv = 1.f / (e0 + e1 + e2);
    const float* imp = ws + IMP_OFF;
    out[1 + idx] = (e0 * imp[idx] + e1 * imp[BTFn + idx] + e2 * imp[2 * BTFn + idx]) * inv;
}

// ---------------- final loss (384 per-chain partials) ----------------
__global__ void loss_final(const float* __restrict__ ws,
                           const float* __restrict__ W_comb,
                           float* __restrict__ out) {
    int tid = threadIdx.x;
    __shared__ float red[512];
    const float* lp = ws + LOSS_OFF;
    red[tid] = (tid < 384) ? lp[tid] : 0.f;
    __syncthreads();
    for (int off = 256; off > 0; off >>= 1) {
        if (tid < off) red[tid] += red[tid + off];
        __syncthreads();
    }
    if (tid == 0) {
        float w0 = W_comb[0], w1 = W_comb[1], w2 = W_comb[2];
        float mx = fmaxf(w0, fmaxf(w1, w2));
        float e0 = expf(w0 - mx), e1 = expf(w1 - mx), e2 = expf(w2 - mx);
        float inv = 1.f / (e0 + e1 + e2);
        float wk0 = e0 * inv, wk1 = e1 * inv, wk2 = e2 * inv;
        float reg = 0.1f * (wk0 * (1.f / 24.f) + wk1 * (1.f / 168.f) + wk2 * (1.f / 720.f));
        out[0] = red[0] + (float)Tn * reg;
    }
}

extern "C" void kernel_launch(void* const* d_in, const int* in_sizes, int n_in,
                              void* d_out, int out_size, void* d_ws, size_t ws_size,
                              hipStream_t stream) {
    const float* data   = (const float*)d_in[0];
    const float* W_dh   = (const float*)d_in[1];
    const float* b_dh   = (const float*)d_in[2];
    const float* W_dx   = (const float*)d_in[3];
    const float* b_dx   = (const float*)d_in[4];
    const float* W_hist = (const float*)d_in[5];
    const float* b_hist = (const float*)d_in[6];
    const float* W_feat = (const float*)d_in[7];
    const float* b_feat = (const float*)d_in[8];
    const float* W_wc   = (const float*)d_in[9];
    const float* b_wc   = (const float*)d_in[10];
    const float* W_ih   = (const float*)d_in[11];
    const float* W_hh   = (const float*)d_in[12];
    const float* b_ih   = (const float*)d_in[13];
    const float* b_hh   = (const float*)d_in[14];
    const float* W_comb = (const float*)d_in[15];
    float* ws = (float*)d_ws;
    float* out = (float*)d_out;

    hipLaunchKernelGGL(prep_kernel, dim3(Tn), dim3(256), 0, stream, data, ws);
    hipLaunchKernelGGL(rits_main, dim3(Bn * 3), dim3(512), SMEM_WORDS * 4, stream,
                       data, W_dh, b_dh, W_dx, b_dx, W_hist, b_hist,
                       W_feat, b_feat, W_wc, b_wc, W_ih, W_hh, b_ih, b_hh, W_comb, ws);
    hipLaunchKernelGGL(impute_reduce, dim3(BTFn / 256), dim3(256), 0, stream, ws, W_comb, out);
    hipLaunchKernelGGL(loss_final, dim3(1), dim3(512), 0, stream, ws, W_comb, out);
}